// Round 4
// baseline (166.502 us; speedup 1.0000x reference)
//
#include <hip/hip_runtime.h>
#include <stdint.h>

#define N_ROWS 8192
#define DDIM   512

typedef __bf16 bf16_t;
typedef bf16_t bf16x8 __attribute__((ext_vector_type(8)));
typedef float  f32x4  __attribute__((ext_vector_type(4)));

#define MFMA_BF16 __builtin_amdgcn_mfma_f32_16x16x32_bf16

// ---------------- f32 -> bf16 (RNE) convert, vectorized ----------------
__device__ inline uint16_t f2bf(float f) {
    uint32_t u = __float_as_uint(f);
    u += 0x7FFFu + ((u >> 16) & 1u);
    return (uint16_t)(u >> 16);
}

__global__ void convert_bf16(const float* __restrict__ a, const float* __restrict__ b,
                             uint16_t* __restrict__ abf, uint16_t* __restrict__ bbf) {
    const int quads = N_ROWS * DDIM / 4;
    const int stride = gridDim.x * blockDim.x;
    for (int i = blockIdx.x * blockDim.x + threadIdx.x; i < quads; i += stride) {
        float4 va = ((const float4*)a)[i];
        float4 vb = ((const float4*)b)[i];
        ushort4 ra, rb;
        ra.x = f2bf(va.x); ra.y = f2bf(va.y); ra.z = f2bf(va.z); ra.w = f2bf(va.w);
        rb.x = f2bf(vb.x); rb.y = f2bf(vb.y); rb.z = f2bf(vb.z); rb.w = f2bf(vb.w);
        ((ushort4*)abf)[i] = ra;
        ((ushort4*)bbf)[i] = rb;
    }
}

// ---------------- async global->LDS 16B stage ----------------
// LDS dest = wave-uniform base + lane*16 (HW-fixed); global source per-lane.
__device__ inline void stage16(const uint8_t* g, uint8_t* lds_wave_base) {
#if __has_builtin(__builtin_amdgcn_global_load_lds)
    __builtin_amdgcn_global_load_lds(
        (const __attribute__((address_space(1))) uint32_t*)g,
        (__attribute__((address_space(3))) uint32_t*)lds_wave_base, 16, 0, 0);
#else
    *(int4*)(lds_wave_base) = *(const int4*)g;
#endif
}

// ============================================================================
// 256x256 tile, BK=64, 8 waves (2x4), double-buffered LDS (128 KB), phased
// schedule with counted vmcnt (never 0 in main loop), per-phase s_barrier,
// setprio around MFMA clusters, XOR bank swizzle on 128B rows (both-sides).
//
// LDS map: buf b at sh + b*65536:  A tile = 256 rows x 128 B   [0, 32768)
//                                  B tile = 256 rows x 128 B   [32768, 65536)
// Row r's granule g (16B, k-chunk) stored at byte r*128 + (g ^ (r&7))*16.
// Stage source permutation supplies granule (t&7)^((t>>3)&7) so the LDS
// write stays linear (base + lane*16).
// ============================================================================
__global__ void __launch_bounds__(512, 2)
clip_gemm(const uint16_t* __restrict__ A, const uint16_t* __restrict__ B,
          const float* __restrict__ scale_p,
          float* __restrict__ rowsum, float* __restrict__ colsum,
          float* __restrict__ diag) {
    __shared__ __attribute__((aligned(16))) uint8_t sh[131072];

    const int t    = threadIdx.x;
    const int wave = t >> 6;
    const int lane = t & 63;
    const int wm   = wave >> 2;    // 0..1  (M half: 128 rows)
    const int wn   = wave & 3;     // 0..3  (N slice: 64 cols)
    const int lr   = lane & 15;
    const int lg   = lane >> 4;

    // XCD band swizzle: xcd = orig&7 owns bm in [xcd*4, xcd*4+4), sweeping bn.
    const int orig = blockIdx.x;               // 0..1023
    const int wg   = (orig & 7) * 128 + (orig >> 3);
    const int bm   = wg >> 5;                  // 0..31
    const int bn   = wg & 31;                  // 0..31

    const float s     = *scale_p;
    const float shift = s - 64.0f;

    f32x4 acc[8][4];
#pragma unroll
    for (int i = 0; i < 8; ++i)
#pragma unroll
        for (int j = 0; j < 4; ++j)
#pragma unroll
            for (int r = 0; r < 4; ++r) acc[i][j][r] = 0.0f;

    // --- staging source (inverse-swizzled): thread t supplies
    //     row = c*64 + (t>>3), granule (t&7)^((t>>3)&7)  of K-tile kt.
    const int g16 = (((t & 7) ^ ((t >> 3) & 7)) << 4);
    const uint8_t* srcA = (const uint8_t*)A + (size_t)(bm * 256 + (t >> 3)) * 1024 + g16;
    const uint8_t* srcB = (const uint8_t*)B + (size_t)(bn * 256 + (t >> 3)) * 1024 + g16;
    uint8_t* dA = sh + wave * 1024;            // + bsel*65536 + c*8192
    uint8_t* dB = sh + 32768 + wave * 1024;

#define STAGE_TILE(kt, bsel) do {                                              \
        const size_t ko = (size_t)(kt) * 128;                                  \
        _Pragma("unroll")                                                      \
        for (int c = 0; c < 4; ++c) {                                          \
            stage16(srcA + ko + (size_t)c * 65536, dA + (bsel) * 65536 + c * 8192); \
            stage16(srcB + ko + (size_t)c * 65536, dB + (bsel) * 65536 + c * 8192); \
        }                                                                      \
    } while (0)

    // --- fragment read offsets (swizzled): chunk (kk*4+lg) ^ (row&7), row&7 = lane&7
    const int x0   = ((lg) ^ (lane & 7)) << 4;
    const int x1   = ((4 | lg) ^ (lane & 7)) << 4;
    const int aoff = (wm * 128 + lr) * 128;
    const int boff = 32768 + (wn * 64 + lr) * 128;

    // ---------------- prologue: stage tiles 0,1 ----------------
    STAGE_TILE(0, 0);
    STAGE_TILE(1, 1);
    asm volatile("s_waitcnt vmcnt(8)" ::: "memory");   // tile 0 resident
    __builtin_amdgcn_s_barrier();

    // ---------------- main loop: 8 K-tiles of 64 ----------------
    for (int tt = 0; tt < 8; ++tt) {
        const uint8_t* base = sh + (tt & 1) * 65536;
        const uint8_t* pA0 = base + aoff + x0;
        const uint8_t* pA1 = base + aoff + x1;
        const uint8_t* pB0 = base + boff + x0;
        const uint8_t* pB1 = base + boff + x1;

        bf16x8 a[4][2], b[4][2];

        // ---- P1: read A-half0 (i=0..3) + B j=0,1 ; MFMA quadrant (i0-3, j0-1)
#pragma unroll
        for (int i = 0; i < 4; ++i) {
            a[i][0] = *(const bf16x8*)(pA0 + i * 2048);
            a[i][1] = *(const bf16x8*)(pA1 + i * 2048);
        }
#pragma unroll
        for (int j = 0; j < 2; ++j) {
            b[j][0] = *(const bf16x8*)(pB0 + j * 2048);
            b[j][1] = *(const bf16x8*)(pB1 + j * 2048);
        }
        __builtin_amdgcn_s_barrier();
        __builtin_amdgcn_s_setprio(1);
#pragma unroll
        for (int i = 0; i < 4; ++i)
#pragma unroll
            for (int j = 0; j < 2; ++j) {
                acc[i][j] = MFMA_BF16(a[i][0], b[j][0], acc[i][j], 0, 0, 0);
                acc[i][j] = MFMA_BF16(a[i][1], b[j][1], acc[i][j], 0, 0, 0);
            }
        __builtin_amdgcn_s_setprio(0);
        __builtin_amdgcn_s_barrier();

        // ---- P2: read B j=2,3 ; MFMA quadrant (i0-3, j2-3)
#pragma unroll
        for (int j = 2; j < 4; ++j) {
            b[j][0] = *(const bf16x8*)(pB0 + j * 2048);
            b[j][1] = *(const bf16x8*)(pB1 + j * 2048);
        }
        __builtin_amdgcn_s_barrier();
        __builtin_amdgcn_s_setprio(1);
#pragma unroll
        for (int i = 0; i < 4; ++i)
#pragma unroll
            for (int j = 2; j < 4; ++j) {
                acc[i][j] = MFMA_BF16(a[i][0], b[j][0], acc[i][j], 0, 0, 0);
                acc[i][j] = MFMA_BF16(a[i][1], b[j][1], acc[i][j], 0, 0, 0);
            }
        __builtin_amdgcn_s_setprio(0);
        __builtin_amdgcn_s_barrier();

        // ---- P3: read A-half1 (i=4..7) ; MFMA quadrant (i4-7, j0-1)
#pragma unroll
        for (int i = 0; i < 4; ++i) {
            a[i][0] = *(const bf16x8*)(pA0 + 8192 + i * 2048);
            a[i][1] = *(const bf16x8*)(pA1 + 8192 + i * 2048);
        }
        __builtin_amdgcn_s_barrier();
        __builtin_amdgcn_s_setprio(1);
#pragma unroll
        for (int i = 0; i < 4; ++i)
#pragma unroll
            for (int j = 0; j < 2; ++j) {
                acc[4 + i][j] = MFMA_BF16(a[i][0], b[j][0], acc[4 + i][j], 0, 0, 0);
                acc[4 + i][j] = MFMA_BF16(a[i][1], b[j][1], acc[4 + i][j], 0, 0, 0);
            }
        __builtin_amdgcn_s_setprio(0);
        __builtin_amdgcn_s_barrier();

        // ---- P4: issue prefetch of tile tt+2 into this (fully-read) buffer,
        //          then MFMA quadrant (i4-7, j2-3). Counted vmcnt: never 0
        //          until the tail.
        if (tt < 6) STAGE_TILE(tt + 2, tt & 1);
        __builtin_amdgcn_s_setprio(1);
#pragma unroll
        for (int i = 0; i < 4; ++i)
#pragma unroll
            for (int j = 2; j < 4; ++j) {
                acc[4 + i][j] = MFMA_BF16(a[i][0], b[j][0], acc[4 + i][j], 0, 0, 0);
                acc[4 + i][j] = MFMA_BF16(a[i][1], b[j][1], acc[4 + i][j], 0, 0, 0);
            }
        __builtin_amdgcn_s_setprio(0);
        if (tt < 6) {
            asm volatile("s_waitcnt vmcnt(8)" ::: "memory");  // tile tt+1 resident
            __builtin_amdgcn_s_barrier();
        } else if (tt == 6) {
            asm volatile("s_waitcnt vmcnt(0)" ::: "memory");  // tile 7 resident
            __builtin_amdgcn_s_barrier();
        }
    }
#undef STAGE_TILE

    // ---------------- epilogue: exp + reductions ----------------
    // D layout: col = lr, row = lg*4 + r (verified R1).
    float cp[4] = {0.f, 0.f, 0.f, 0.f};
#pragma unroll
    for (int i = 0; i < 8; ++i) {
        float rp[4] = {0.f, 0.f, 0.f, 0.f};
#pragma unroll
        for (int j = 0; j < 4; ++j) {
#pragma unroll
            for (int r = 0; r < 4; ++r) {
                const float logit = s * acc[i][j][r];
                const float e = __expf(logit - shift);
                rp[r] += e;
                cp[j] += e;
                if (bm == bn) {
                    const int rr = wm * 128 + i * 16 + lg * 4 + r;
                    const int cc = wn * 64 + j * 16 + lr;
                    if (rr == cc) diag[bm * 256 + rr] = logit;
                }
            }
        }
#pragma unroll
        for (int r = 0; r < 4; ++r) {
            float v = rp[r];
            v += __shfl_xor(v, 1);
            v += __shfl_xor(v, 2);
            v += __shfl_xor(v, 4);
            v += __shfl_xor(v, 8);
            if (lr == 0)
                atomicAdd(&rowsum[bm * 256 + wm * 128 + i * 16 + lg * 4 + r], v);
        }
    }
#pragma unroll
    for (int j = 0; j < 4; ++j) {
        float v = cp[j];
        v += __shfl_xor(v, 16);
        v += __shfl_xor(v, 32);
        if (lg == 0)
            atomicAdd(&colsum[bn * 256 + wn * 64 + j * 16 + lr], v);
    }
}

// ---------------- final reduce: loss scalar (parallel) ----------------
__global__ void clip_finalize(const float* __restrict__ rowsum, const float* __restrict__ colsum,
                              const float* __restrict__ diag, const float* __restrict__ scale_p,
                              float* __restrict__ out) {
    __shared__ float red[4];
    const float s = *scale_p;
    const float shift = s - 64.0f;
    const int i = blockIdx.x * 256 + threadIdx.x;   // grid 32 x 256 = 8192
    float acc = logf(rowsum[i]) + logf(colsum[i]) + 2.f * shift - 2.f * diag[i];
#pragma unroll
    for (int m = 1; m < 64; m <<= 1) acc += __shfl_xor(acc, m);
    const int wave = threadIdx.x >> 6;
    const int lane = threadIdx.x & 63;
    if (lane == 0) red[wave] = acc;
    __syncthreads();
    if (threadIdx.x == 0) {
        atomicAdd(out, (red[0] + red[1] + red[2] + red[3]) / (2.0f * N_ROWS));
    }
}

extern "C" void kernel_launch(void* const* d_in, const int* in_sizes, int n_in,
                              void* d_out, int out_size, void* d_ws, size_t ws_size,
                              hipStream_t stream) {
    const float* img     = (const float*)d_in[0];
    const float* txt     = (const float*)d_in[1];
    const float* scale_p = (const float*)d_in[2];

    uint8_t* ws = (uint8_t*)d_ws;
    uint16_t* Abf   = (uint16_t*)ws;                                  // 8 MB
    uint16_t* Bbf   = (uint16_t*)(ws + (size_t)8 * 1024 * 1024);      // 8 MB
    float*    rowsum = (float*)(ws + (size_t)16 * 1024 * 1024);       // 32 KB
    float*    colsum = rowsum + N_ROWS;                               // 32 KB
    float*    diag   = colsum + N_ROWS;                               // 32 KB
    float*    out    = (float*)d_out;

    hipMemsetAsync(rowsum, 0, 2 * N_ROWS * sizeof(float), stream);
    hipMemsetAsync(out, 0, sizeof(float), stream);
    convert_bf16<<<1024, 256, 0, stream>>>(img, txt, Abf, Bbf);
    clip_gemm<<<1024, 512, 0, stream>>>(Abf, Bbf, scale_p, rowsum, colsum, diag);
    clip_finalize<<<32, 256, 0, stream>>>(rowsum, colsum, diag, scale_p, out);
}

// Round 5
// 106.753 us; speedup vs baseline: 1.5597x; 1.5597x over previous
//
#include <hip/hip_runtime.h>
#include <stdint.h>

#define N_ROWS 8192
#define DDIM   512

typedef __bf16 bf16_t;
typedef bf16_t bf16x8 __attribute__((ext_vector_type(8)));
typedef float  f32x4  __attribute__((ext_vector_type(4)));

#define MFMA_BF16 __builtin_amdgcn_mfma_f32_16x16x32_bf16

// ---------------- f32 -> bf16 (RNE) convert, vectorized ----------------
__device__ inline uint16_t f2bf(float f) {
    uint32_t u = __float_as_uint(f);
    u += 0x7FFFu + ((u >> 16) & 1u);
    return (uint16_t)(u >> 16);
}

__global__ void convert_bf16(const float* __restrict__ a, const float* __restrict__ b,
                             uint16_t* __restrict__ abf, uint16_t* __restrict__ bbf) {
    const int quads = N_ROWS * DDIM / 4;
    const int stride = gridDim.x * blockDim.x;
    for (int i = blockIdx.x * blockDim.x + threadIdx.x; i < quads; i += stride) {
        float4 va = ((const float4*)a)[i];
        float4 vb = ((const float4*)b)[i];
        ushort4 ra, rb;
        ra.x = f2bf(va.x); ra.y = f2bf(va.y); ra.z = f2bf(va.z); ra.w = f2bf(va.w);
        rb.x = f2bf(vb.x); rb.y = f2bf(vb.y); rb.z = f2bf(vb.z); rb.w = f2bf(vb.w);
        ((ushort4*)abf)[i] = ra;
        ((ushort4*)bbf)[i] = rb;
    }
}

// ---------------- async global->LDS 16B stage ----------------
__device__ inline void stage16(const uint8_t* g, uint8_t* lds_wave_base) {
#if __has_builtin(__builtin_amdgcn_global_load_lds)
    __builtin_amdgcn_global_load_lds(
        (const __attribute__((address_space(1))) uint32_t*)g,
        (__attribute__((address_space(3))) uint32_t*)lds_wave_base, 16, 0, 0);
#else
    *(int4*)(lds_wave_base) = *(const int4*)g;
#endif
}

// ============================================================================
// 256x256 tile, BK=64, 8 waves (2Mx4N), double-buffered LDS (128 KB), 4-phase
// schedule, counted vmcnt (never 0 in main loop), setprio around MFMA,
// XOR bank swizzle on 128B rows (both-sides), 2D-chunked XCD block swizzle.
//
// LDS: buf b at sh + b*65536: A = 256 rows x 128 B  [0,32768)
//                             B = 256 rows x 128 B  [32768,65536)
// Row r granule g (16B) at byte r*128 + (g ^ (r&7))*16; staging source
// supplies granule (t&7)^((t>>3)&7) so the LDS dest stays linear.
// Staging granule c = 64 rows (c*64 .. c*64+63) = one wave-uniform 1KB/wave op.
// ============================================================================
__global__ void __launch_bounds__(512, 2)
clip_gemm(const uint16_t* __restrict__ A, const uint16_t* __restrict__ B,
          const float* __restrict__ scale_p,
          float* __restrict__ rowsum, float* __restrict__ colsum,
          float* __restrict__ diag) {
    __shared__ __attribute__((aligned(16))) uint8_t sh[131072];

    const int t    = threadIdx.x;
    const int wave = t >> 6;
    const int lane = t & 63;
    const int wm   = wave >> 2;    // 0..1  (M half: 128 rows)
    const int wn   = wave & 3;     // 0..3  (N slice: 64 cols)
    const int lr   = lane & 15;
    const int lg   = lane >> 4;

    // 2D-chunked XCD swizzle: xcd owns an 8bm x 16bn rectangle, bm-fastest.
    // Concurrent 32 blocks/XCD cover 8bm x 4bn -> 3 MB L2 working set.
    const int orig = blockIdx.x;               // 0..1023
    const int xcd  = orig & 7;
    const int idx  = orig >> 3;                // 0..127
    const int bm   = (xcd & 3) * 8  + (idx & 7);
    const int bn   = (xcd >> 2) * 16 + (idx >> 3);

    const float s     = *scale_p;
    const float shift = s - 64.0f;

    f32x4 acc[8][4];
#pragma unroll
    for (int i = 0; i < 8; ++i)
#pragma unroll
        for (int j = 0; j < 4; ++j)
#pragma unroll
            for (int r = 0; r < 4; ++r) acc[i][j][r] = 0.0f;

    // staging source (inverse-swizzled): thread t supplies row c*64+(t>>3),
    // granule (t&7)^((t>>3)&7) of K-tile kt.
    const int g16 = (((t & 7) ^ ((t >> 3) & 7)) << 4);
    const uint8_t* srcA = (const uint8_t*)A + (size_t)(bm * 256 + (t >> 3)) * 1024 + g16;
    const uint8_t* srcB = (const uint8_t*)B + (size_t)(bn * 256 + (t >> 3)) * 1024 + g16;
    uint8_t* dA = sh + wave * 1024;
    uint8_t* dB = sh + 32768 + wave * 1024;

#define STAGE_A(kt, bsel, c) stage16(srcA + (size_t)(kt) * 128 + (size_t)(c) * 65536, \
                                     dA + (bsel) * 65536 + (c) * 8192)
#define STAGE_B(kt, bsel, c) stage16(srcB + (size_t)(kt) * 128 + (size_t)(c) * 65536, \
                                     dB + (bsel) * 65536 + (c) * 8192)

    // fragment read offsets (swizzled): chunk (kk*4+lg) ^ (lane&7)
    const int x0   = ((lg) ^ (lane & 7)) << 4;
    const int x1   = ((4 | lg) ^ (lane & 7)) << 4;
    const int aoff = (wm * 128 + lr) * 128;
    const int boff = 32768 + (wn * 64 + lr) * 128;

    // ---------------- prologue: stage tiles 0,1 ----------------
#pragma unroll
    for (int c = 0; c < 4; ++c) { STAGE_A(0, 0, c); STAGE_B(0, 0, c); }
#pragma unroll
    for (int c = 0; c < 4; ++c) { STAGE_A(1, 1, c); STAGE_B(1, 1, c); }
    asm volatile("s_waitcnt vmcnt(8)" ::: "memory");   // tile 0 resident
    __builtin_amdgcn_s_barrier();

    // ---------------- main loop: 8 K-tiles of 64 ----------------
    for (int tt = 0; tt < 8; ++tt) {
        const uint8_t* base = sh + (tt & 1) * 65536;
        const uint8_t* pA0 = base + aoff + x0;
        const uint8_t* pA1 = base + aoff + x1;
        const uint8_t* pB0 = base + boff + x0;
        const uint8_t* pB1 = base + boff + x1;

        bf16x8 a[4][2], b[4][2];

        // ---- P1: read A-half0 + B j0,1 ; MFMA (i0-3, j0-1)
        //      A rows {wm*128 + 0..63} -> granules 0,2 fully read after P1.
#pragma unroll
        for (int i = 0; i < 4; ++i) {
            a[i][0] = *(const bf16x8*)(pA0 + i * 2048);
            a[i][1] = *(const bf16x8*)(pA1 + i * 2048);
        }
#pragma unroll
        for (int j = 0; j < 2; ++j) {
            b[j][0] = *(const bf16x8*)(pB0 + j * 2048);
            b[j][1] = *(const bf16x8*)(pB1 + j * 2048);
        }
        __builtin_amdgcn_s_barrier();
        __builtin_amdgcn_s_setprio(1);
#pragma unroll
        for (int i = 0; i < 4; ++i)
#pragma unroll
            for (int j = 0; j < 2; ++j) {
                acc[i][j] = MFMA_BF16(a[i][0], b[j][0], acc[i][j], 0, 0, 0);
                acc[i][j] = MFMA_BF16(a[i][1], b[j][1], acc[i][j], 0, 0, 0);
            }
        __builtin_amdgcn_s_setprio(0);
        __builtin_amdgcn_s_barrier();

        // ---- P2: read B j2,3 ; prefetch A granules 0,2 of tile tt+2 ;
        //          MFMA (i0-3, j2-3). B fully read after this phase.
#pragma unroll
        for (int j = 2; j < 4; ++j) {
            b[j][0] = *(const bf16x8*)(pB0 + j * 2048);
            b[j][1] = *(const bf16x8*)(pB1 + j * 2048);
        }
        if (tt < 6) { STAGE_A(tt + 2, tt & 1, 0); STAGE_A(tt + 2, tt & 1, 2); }
        __builtin_amdgcn_s_barrier();
        __builtin_amdgcn_s_setprio(1);
#pragma unroll
        for (int i = 0; i < 4; ++i)
#pragma unroll
            for (int j = 2; j < 4; ++j) {
                acc[i][j] = MFMA_BF16(a[i][0], b[j][0], acc[i][j], 0, 0, 0);
                acc[i][j] = MFMA_BF16(a[i][1], b[j][1], acc[i][j], 0, 0, 0);
            }
        __builtin_amdgcn_s_setprio(0);
        __builtin_amdgcn_s_barrier();

        // ---- P3: read A-half1 ; prefetch B granules 0-3 of tile tt+2 ;
        //          MFMA (i4-7, j0-1). A fully read after this phase.
#pragma unroll
        for (int i = 0; i < 4; ++i) {
            a[i][0] = *(const bf16x8*)(pA0 + 8192 + i * 2048);
            a[i][1] = *(const bf16x8*)(pA1 + 8192 + i * 2048);
        }
        if (tt < 6) {
            STAGE_B(tt + 2, tt & 1, 0); STAGE_B(tt + 2, tt & 1, 1);
            STAGE_B(tt + 2, tt & 1, 2); STAGE_B(tt + 2, tt & 1, 3);
        }
        __builtin_amdgcn_s_barrier();
        __builtin_amdgcn_s_setprio(1);
#pragma unroll
        for (int i = 0; i < 4; ++i)
#pragma unroll
            for (int j = 0; j < 2; ++j) {
                acc[4 + i][j] = MFMA_BF16(a[i][0], b[j][0], acc[4 + i][j], 0, 0, 0);
                acc[4 + i][j] = MFMA_BF16(a[i][1], b[j][1], acc[4 + i][j], 0, 0, 0);
            }
        __builtin_amdgcn_s_setprio(0);
        __builtin_amdgcn_s_barrier();

        // ---- P4: prefetch A granules 1,3 ; MFMA (i4-7, j2-3) ; counted wait.
        if (tt < 6) { STAGE_A(tt + 2, tt & 1, 1); STAGE_A(tt + 2, tt & 1, 3); }
        __builtin_amdgcn_s_setprio(1);
#pragma unroll
        for (int i = 0; i < 4; ++i)
#pragma unroll
            for (int j = 2; j < 4; ++j) {
                acc[4 + i][j] = MFMA_BF16(a[i][0], b[j][0], acc[4 + i][j], 0, 0, 0);
                acc[4 + i][j] = MFMA_BF16(a[i][1], b[j][1], acc[4 + i][j], 0, 0, 0);
            }
        __builtin_amdgcn_s_setprio(0);
        if (tt < 6) {
            asm volatile("s_waitcnt vmcnt(8)" ::: "memory");  // tile tt+1 resident
            __builtin_amdgcn_s_barrier();
        } else if (tt == 6) {
            asm volatile("s_waitcnt vmcnt(0)" ::: "memory");  // tile 7 resident
            __builtin_amdgcn_s_barrier();
        }
    }
#undef STAGE_A
#undef STAGE_B

    // ---------------- epilogue: exp + reductions ----------------
    // D layout: col = lr, row = lg*4 + r.
    float cp[4] = {0.f, 0.f, 0.f, 0.f};
#pragma unroll
    for (int i = 0; i < 8; ++i) {
        float rp[4] = {0.f, 0.f, 0.f, 0.f};
#pragma unroll
        for (int j = 0; j < 4; ++j) {
#pragma unroll
            for (int r = 0; r < 4; ++r) {
                const float logit = s * acc[i][j][r];
                const float e = __expf(logit - shift);
                rp[r] += e;
                cp[j] += e;
                if (bm == bn) {
                    const int rr = wm * 128 + i * 16 + lg * 4 + r;
                    const int cc = wn * 64 + j * 16 + lr;
                    if (rr == cc) diag[bm * 256 + rr] = logit;
                }
            }
        }
#pragma unroll
        for (int r = 0; r < 4; ++r) {
            float v = rp[r];
            v += __shfl_xor(v, 1);
            v += __shfl_xor(v, 2);
            v += __shfl_xor(v, 4);
            v += __shfl_xor(v, 8);
            if (lr == 0)
                atomicAdd(&rowsum[bm * 256 + wm * 128 + i * 16 + lg * 4 + r], v);
        }
    }
#pragma unroll
    for (int j = 0; j < 4; ++j) {
        float v = cp[j];
        v += __shfl_xor(v, 16);
        v += __shfl_xor(v, 32);
        if (lg == 0)
            atomicAdd(&colsum[bn * 256 + wn * 64 + j * 16 + lr], v);
    }
}

// ---------------- final reduce: loss scalar (parallel) ----------------
__global__ void clip_finalize(const float* __restrict__ rowsum, const float* __restrict__ colsum,
                              const float* __restrict__ diag, const float* __restrict__ scale_p,
                              float* __restrict__ out) {
    __shared__ float red[4];
    const float s = *scale_p;
    const float shift = s - 64.0f;
    const int i = blockIdx.x * 256 + threadIdx.x;   // grid 32 x 256 = 8192
    float acc = logf(rowsum[i]) + logf(colsum[i]) + 2.f * shift - 2.f * diag[i];
#pragma unroll
    for (int m = 1; m < 64; m <<= 1) acc += __shfl_xor(acc, m);
    const int wave = threadIdx.x >> 6;
    const int lane = threadIdx.x & 63;
    if (lane == 0) red[wave] = acc;
    __syncthreads();
    if (threadIdx.x == 0) {
        atomicAdd(out, (red[0] + red[1] + red[2] + red[3]) / (2.0f * N_ROWS));
    }
}

extern "C" void kernel_launch(void* const* d_in, const int* in_sizes, int n_in,
                              void* d_out, int out_size, void* d_ws, size_t ws_size,
                              hipStream_t stream) {
    const float* img     = (const float*)d_in[0];
    const float* txt     = (const float*)d_in[1];
    const float* scale_p = (const float*)d_in[2];

    uint8_t* ws = (uint8_t*)d_ws;
    uint16_t* Abf   = (uint16_t*)ws;                                  // 8 MB
    uint16_t* Bbf   = (uint16_t*)(ws + (size_t)8 * 1024 * 1024);      // 8 MB
    float*    rowsum = (float*)(ws + (size_t)16 * 1024 * 1024);       // 32 KB
    float*    colsum = rowsum + N_ROWS;                               // 32 KB
    float*    diag   = colsum + N_ROWS;                               // 32 KB
    float*    out    = (float*)d_out;

    hipMemsetAsync(rowsum, 0, 2 * N_ROWS * sizeof(float), stream);
    hipMemsetAsync(out, 0, sizeof(float), stream);
    convert_bf16<<<1024, 256, 0, stream>>>(img, txt, Abf, Bbf);
    clip_gemm<<<1024, 512, 0, stream>>>(Abf, Bbf, scale_p, rowsum, colsum, diag);
    clip_finalize<<<32, 256, 0, stream>>>(rowsum, colsum, diag, scale_p, out);
}